// Round 13
// baseline (177.333 us; speedup 1.0000x reference)
//
#include <hip/hip_runtime.h>
#include <hip/hip_bf16.h>
#include <math.h>

typedef __bf16 bf16_8 __attribute__((ext_vector_type(8)));
typedef float f32x4 __attribute__((ext_vector_type(4)));

#define D_ 256
#define S_ 128
#define E_ 512
#define MPE_ 4096
#define B_ 2
#define N_ 4096
#define M_TOT (B_*N_)   // 8192

__device__ __forceinline__ ushort f2b(float f) {
  union { float f; uint u; } x; x.f = f;
  uint r = (x.u + 0x7FFFu + ((x.u >> 16) & 1u)) >> 16;
  return (ushort)r;
}
__device__ __forceinline__ float b2f(ushort b) {
  union { uint u; float f; } x; x.u = ((uint)b) << 16;
  return x.f;
}

__device__ __forceinline__ void gl_lds16(const void* g, void* l) {
  __builtin_amdgcn_global_load_lds(
      (const __attribute__((address_space(1))) void*)g,
      (__attribute__((address_space(3))) void*)l, 16, 0, 0);
}

// ---------------- LayerNorm: one wave per row ----------------
__global__ __launch_bounds__(256) void ln_kernel(const float* __restrict__ q,
    const float* __restrict__ w, const float* __restrict__ b,
    ushort* __restrict__ x) {
  int wid = threadIdx.x >> 6, lane = threadIdx.x & 63;
  int row = blockIdx.x * 4 + wid;
  const float* qr = q + (size_t)row * D_;
  float4 v = *(const float4*)(qr + lane * 4);
  float s  = v.x + v.y + v.z + v.w;
  float ss = v.x*v.x + v.y*v.y + v.z*v.z + v.w*v.w;
  #pragma unroll
  for (int off = 32; off; off >>= 1) {
    s  += __shfl_xor(s, off);
    ss += __shfl_xor(ss, off);
  }
  float mu   = s * (1.0f / 256.0f);
  float var  = ss * (1.0f / 256.0f) - mu * mu;
  float rstd = rsqrtf(var + 1e-5f);
  ushort4 o;
  float vv[4] = {v.x, v.y, v.z, v.w};
  ushort ot[4];
  #pragma unroll
  for (int j = 0; j < 4; ++j) {
    int c = lane * 4 + j;
    ot[j] = f2b((vv[j] - mu) * rstd * w[c] + b[c]);
  }
  o.x = ot[0]; o.y = ot[1]; o.z = ot[2]; o.w = ot[3];
  *(ushort4*)(x + (size_t)row * D_ + lane * 4) = o;
}

// ---------------- prep: all 4 weight transposes + wrep in ONE launch ----------------
__global__ __launch_bounds__(256) void prep_kernel(
    const float* __restrict__ Wu, const float* __restrict__ Wv,
    const float* __restrict__ Wb, const float* __restrict__ Wo,
    const float* __restrict__ w_rel,
    ushort* __restrict__ WUT, ushort* __restrict__ WVT,
    ushort* __restrict__ WBT, ushort* __restrict__ WOT,
    float* __restrict__ wrep) {
  int blk = blockIdx.x, tid = threadIdx.x;
  if (blk < 512) {
    int o = blk * 256 + tid; int c = o >> 8, r = o & 255;
    WUT[o] = f2b(Wu[r * 512 + c]);
  } else if (blk < 1024) {
    int o = (blk - 512) * 256 + tid; int c = o >> 8, r = o & 255;
    WVT[o] = f2b(Wv[r * 512 + c]);
  } else if (blk < 1152) {
    int o = (blk - 1024) * 256 + tid; int c = o >> 8, r = o & 255;
    WBT[o] = f2b(Wb[r * 128 + c]);
  } else if (blk < 1664) {
    int o = (blk - 1152) * 256 + tid; int c = o >> 9, r = o & 511;
    WOT[o] = f2b(Wo[r * 256 + c]);
  } else {
    int idx = (blk - 1664) * 256 + tid;
    int c = idx >> 13, i = idx & 8191;
    int s = i + c; if (s > 8190) s = 8190;
    wrep[idx] = w_rel[s];
  }
}

// ---------------- GEMM: A[M][K] bf16, Bt[N][K] bf16, tile 128x64, BK=64 ----------------
template<int EPI>
__global__ __launch_bounds__(256) void gemm_kernel(
    const ushort* __restrict__ A, const ushort* __restrict__ Bt,
    const float* __restrict__ bias, void* __restrict__ out,
    int M, int N, int K) {
  __shared__ alignas(16) ushort As[128 * 64];
  __shared__ alignas(16) ushort Bs[64 * 64];
  int tid = threadIdx.x;
  int lane = tid & 63, wid = tid >> 6;
  int m0 = blockIdx.x * 128, n0 = blockIdx.y * 64;
  int r16 = lane & 15, kq = lane >> 4;
  f32x4 acc[2][4] = {};
  for (int k0 = 0; k0 < K; k0 += 64) {
    __syncthreads();
    #pragma unroll
    for (int t = 0; t < 4; ++t) {
      int cid = tid + t * 256;
      int row = cid >> 3, c = cid & 7;
      uint4 d = *(const uint4*)(A + ((size_t)(m0 + row) * K + k0 + c * 8));
      *(uint4*)&As[row * 64 + ((c ^ (row & 7)) * 8)] = d;
    }
    #pragma unroll
    for (int t = 0; t < 2; ++t) {
      int cid = tid + t * 256;
      int row = cid >> 3, c = cid & 7;
      uint4 d = *(const uint4*)(Bt + ((size_t)(n0 + row) * K + k0 + c * 8));
      *(uint4*)&Bs[row * 64 + ((c ^ (row & 7)) * 8)] = d;
    }
    __syncthreads();
    #pragma unroll
    for (int ks = 0; ks < 2; ++ks) {
      bf16_8 af[2], bfr[4];
      int c = ks * 4 + kq;
      #pragma unroll
      for (int fm = 0; fm < 2; ++fm) {
        int r = wid * 32 + fm * 16 + r16;
        af[fm] = *(const bf16_8*)&As[r * 64 + ((c ^ (r & 7)) * 8)];
      }
      #pragma unroll
      for (int fn = 0; fn < 4; ++fn) {
        int r = fn * 16 + r16;
        bfr[fn] = *(const bf16_8*)&Bs[r * 64 + ((c ^ (r & 7)) * 8)];
      }
      #pragma unroll
      for (int fm = 0; fm < 2; ++fm)
        #pragma unroll
        for (int fn = 0; fn < 4; ++fn)
          acc[fm][fn] = __builtin_amdgcn_mfma_f32_16x16x32_bf16(af[fm], bfr[fn], acc[fm][fn], 0, 0, 0);
    }
  }
  #pragma unroll
  for (int fm = 0; fm < 2; ++fm)
    #pragma unroll
    for (int fn = 0; fn < 4; ++fn)
      #pragma unroll
      for (int reg = 0; reg < 4; ++reg) {
        int ml = wid * 32 + fm * 16 + kq * 4 + reg;
        int nl = fn * 16 + r16;
        size_t gm = m0 + ml, gn = n0 + nl;
        float val = acc[fm][fn][reg] + bias[gn];
        if (EPI == 0) {
          float y = val / (1.0f + expf(-val));
          ((ushort*)out)[gm * N + gn] = f2b(y);
        } else if (EPI == 2) {
          float y = val / (1.0f + expf(-val));
          ((ushort*)out)[gn * (size_t)M_TOT + gm] = f2b(y);
        } else {
          ((float*)out)[gm * N + gn] = val;
        }
      }
}

// ---------------- RoPE (outputs pre-scaled by 1/64 so q.k carries 1/MPE) ----------------
__global__ __launch_bounds__(256) void rope_kernel(const ushort* __restrict__ base,
    const float* __restrict__ qw, const float* __restrict__ qb,
    const float* __restrict__ kw, const float* __restrict__ kb,
    ushort* __restrict__ Q, ushort* __restrict__ Kk) {
  int g = blockIdx.x * 256 + threadIdx.x;
  int row = g >> 6, i = g & 63;
  int n = row & (N_ - 1);
  float invf = powf(10000.0f, -(float)i * (1.0f / 64.0f));
  float sv, cv;
  sincosf((float)n * invf, &sv, &cv);
  const float sc = 0.015625f;   // 1/64; (1/64)^2 = 1/4096 = 1/MPE
  float b1 = b2f(base[row * S_ + i]), b2 = b2f(base[row * S_ + 64 + i]);
  float x1q = b1 * qw[i] + qb[i], x2q = b2 * qw[64 + i] + qb[64 + i];
  Q[row * S_ + i]      = f2b((x1q * cv - x2q * sv) * sc);
  Q[row * S_ + 64 + i] = f2b((x2q * cv + x1q * sv) * sc);
  float x1k = b1 * kw[i] + kb[i], x2k = b2 * kw[64 + i] + kb[64 + i];
  Kk[row * S_ + i]      = f2b((x1k * cv - x2k * sv) * sc);
  Kk[row * S_ + 64 + i] = f2b((x2k * cv + x1k * sv) * sc);
}

// ---------------- fused attention: R6 structure, 3-phase counted-vmcnt schedule ----------------
// grid (32 m-tiles of 128, 4 e-chunks of 128, 2 b), 512 thr (8 waves), 96KB LDS.
// Per iter t: ph1 {bias + stage K(t+1),V(t) issue || kf reads} -> QK -> vmcnt(8)+bar;
// ph2 {pa/vf reads} -> PV(t-1) -> bar; ph3 transform -> P(t) write -> lgkm0,vmcnt(2)+bar.
// Outstanding-op ledger (per wave, per iter: 4 bias + 2 K + 2 V = 8 VMEM):
//   vmcnt(8) => V(t-1) landed (8 newer ops); vmcnt(2) => K(t+1) landed (V(t) may fly).
// No vmcnt(0) in the loop: stages stay in flight across all 3 barriers (T3+T4).
__global__ __launch_bounds__(512, 2) void attn_kernel(
    const ushort* __restrict__ Q, const ushort* __restrict__ Kd,
    const ushort* __restrict__ VT, const ushort* __restrict__ U,
    const float* __restrict__ wrep, ushort* __restrict__ KVU) {
  __shared__ alignas(16) ushort Ks[2][64 * 128];   // 32 KB
  __shared__ alignas(16) ushort Vs[2][128 * 64];   // 32 KB
  __shared__ alignas(16) ushort Pb[2][128 * 64];   // 32 KB
  const int tid = threadIdx.x, lane = tid & 63, wid = tid >> 6;
  const int b = blockIdx.z, m0 = blockIdx.x * 128, e0 = blockIdx.y * 128;
  const int r16 = lane & 15, kq = lane >> 4;
  const int wqm = wid >> 2, wqn = wid & 3;   // QK: 2m x 4n
  const int wpm = wid >> 1, wpe = wid & 1;   // PV: 4m x 2e

  // bias: w_rel idx = bbase + 64t - 16fm + rg, always in [0,8190]; aligned float4 via wrep
  const int bbase = 4095 + 16 * wqn + 4 * kq - m0 - 64 * wqm - r16;
  const int csel = bbase & 3;
  const float* wrow = wrep + csel * 8192 + (bbase - csel);

  // Q fragments: wave's 64 m-rows x 128 k (B-operand: col=m)
  bf16_8 qf[4][4];
  #pragma unroll
  for (int fm = 0; fm < 4; ++fm)
    #pragma unroll
    for (int ks = 0; ks < 4; ++ks)
      qf[fm][ks] = *(const bf16_8*)(Q +
          ((size_t)(b * N_ + m0 + wqm * 64 + fm * 16 + r16) * S_ + ks * 32 + kq * 8));

  auto stage_k = [&](int bi, int nt) {
    int n0s = nt * 64;
    #pragma unroll
    for (int tt = 0; tt < 2; ++tt) {           // 64n x 128k = 1024 chunks / 512 thr
      int p = tt * 512 + tid;
      int row = p >> 4, sc2 = p & 15;
      int cc = sc2 ^ (row & 7);
      gl_lds16(Kd + ((size_t)(b * N_ + n0s + row) * S_ + cc * 8),
               &Ks[bi][(tt * 512 + wid * 64) * 8]);
    }
  };
  auto stage_v = [&](int bi, int nt) {
    int n0s = nt * 64;
    #pragma unroll
    for (int tt = 0; tt < 2; ++tt) {           // 128e x 64n = 1024 chunks
      int p = tt * 512 + tid;
      int er = p >> 3, sc2 = p & 7;
      int nc = sc2 ^ (er & 7);
      gl_lds16(VT + ((size_t)(e0 + er) * M_TOT + b * N_ + n0s + nc * 8),
               &Vs[bi][(tt * 512 + wid * 64) * 8]);
    }
  };

  f32x4 pv[2][4] = {};

  auto do_pv = [&](int pi) {
    const char* psb = (const char*)&Pb[pi][0];
    const ushort* vsb = &Vs[pi][0];
    __builtin_amdgcn_s_setprio(1);
    #pragma unroll
    for (int ks = 0; ks < 2; ++ks) {
      bf16_8 pa[2];
      #pragma unroll
      for (int fm = 0; fm < 2; ++fm) {
        int r = wpm * 32 + fm * 16 + r16;
        pa[fm] = *(const bf16_8*)(psb + ((r * 128 + ks * 64 + kq * 16) ^ ((r & 7) << 4)));
      }
      #pragma unroll
      for (int fe = 0; fe < 4; ++fe) {
        int rv = wpe * 64 + fe * 16 + r16;
        int cv = ks * 4 + kq;
        bf16_8 vf = *(const bf16_8*)&vsb[rv * 64 + ((cv ^ (rv & 7)) * 8)];
        #pragma unroll
        for (int fm = 0; fm < 2; ++fm)
          pv[fm][fe] = __builtin_amdgcn_mfma_f32_16x16x32_bf16(pa[fm], vf, pv[fm][fe], 0, 0, 0);
      }
    }
    __builtin_amdgcn_s_setprio(0);
  };

  // prologue: K(0) staged + drained
  stage_k(0, 0);
  asm volatile("s_waitcnt vmcnt(0) lgkmcnt(0)" ::: "memory");
  __builtin_amdgcn_s_barrier();

  auto body = [&](int CUR, int t) {
    // ---- ph1: bias loads (first!), then stage issues, kf reads, QK ----
    float4 b4[4];
    #pragma unroll
    for (int fm = 0; fm < 4; ++fm)
      b4[fm] = *(const float4*)(wrow + 64 * t - 16 * fm);
    if (t < 63) stage_k(CUR ^ 1, t + 1);
    stage_v(CUR, t);
    __builtin_amdgcn_sched_barrier(0);
    const ushort* ksb = &Ks[CUR][0];
    f32x4 sacc[4] = {};
    __builtin_amdgcn_s_setprio(1);
    #pragma unroll
    for (int ks = 0; ks < 4; ++ks) {
      int r = wqn * 16 + r16;
      int c = ks * 4 + kq;
      bf16_8 kf = *(const bf16_8*)&ksb[r * 128 + ((c ^ (r & 7)) * 8)];
      #pragma unroll
      for (int fm = 0; fm < 4; ++fm)
        sacc[fm] = __builtin_amdgcn_mfma_f32_16x16x32_bf16(kf, qf[fm][ks], sacc[fm], 0, 0, 0);
    }
    __builtin_amdgcn_s_setprio(0);
    asm volatile("s_waitcnt vmcnt(8)" ::: "memory");   // V(t-1) landed
    __builtin_amdgcn_s_barrier();
    // ---- ph2: PV(t-1) from Pb/Vs[CUR^1] ----
    if (t > 0) do_pv(CUR ^ 1);
    __builtin_amdgcn_s_barrier();
    // ---- ph3: transform -> Pb[CUR] ----
    char* psb = (char*)&Pb[CUR][0];
    #pragma unroll
    for (int fm = 0; fm < 4; ++fm) {
      float t0 = fmaxf(sacc[fm][0] + b4[fm].x, 0.f); t0 *= t0;
      float t1 = fmaxf(sacc[fm][1] + b4[fm].y, 0.f); t1 *= t1;
      float t2 = fmaxf(sacc[fm][2] + b4[fm].z, 0.f); t2 *= t2;
      float t3 = fmaxf(sacc[fm][3] + b4[fm].w, 0.f); t3 *= t3;
      uint p01, p23;
      asm("v_cvt_pk_bf16_f32 %0, %1, %2" : "=v"(p01) : "v"(t0), "v"(t1));
      asm("v_cvt_pk_bf16_f32 %0, %1, %2" : "=v"(p23) : "v"(t2), "v"(t3));
      int mp = wqm * 64 + fm * 16 + r16;
      int nb2 = wqn * 32 + kq * 8;
      uint2 pk; pk.x = p01; pk.y = p23;
      *(uint2*)(psb + ((mp * 128 + nb2) ^ ((mp & 7) << 4))) = pk;
    }
    asm volatile("s_waitcnt lgkmcnt(0)" ::: "memory");   // P(t) writes done
    asm volatile("s_waitcnt vmcnt(2)" ::: "memory");     // K(t+1) landed; V(t) may fly
    __builtin_amdgcn_s_barrier();
  };

  for (int t2 = 0; t2 < 32; ++t2) {
    body(0, 2 * t2);
    body(1, 2 * t2 + 1);
  }
  // drain: PV(63)
  asm volatile("s_waitcnt vmcnt(0)" ::: "memory");
  __builtin_amdgcn_s_barrier();
  do_pv(1);

  // ---- epilogue: KVU = bf16(u * pv) ----
  #pragma unroll
  for (int fm = 0; fm < 2; ++fm)
    #pragma unroll
    for (int fe = 0; fe < 4; ++fe)
      #pragma unroll
      for (int reg = 0; reg < 4; ++reg) {
        int ml = wpm * 32 + fm * 16 + kq * 4 + reg;
        size_t grow = (size_t)b * N_ + m0 + ml;
        size_t ge = e0 + wpe * 64 + fe * 16 + r16;
        float uu = b2f(U[grow * E_ + ge]);
        KVU[grow * E_ + ge] = f2b(uu * pv[fm][fe][reg]);
      }
}

extern "C" void kernel_launch(void* const* d_in, const int* in_sizes, int n_in,
                              void* d_out, int out_size, void* d_ws, size_t ws_size,
                              hipStream_t stream) {
  const float* query = (const float*)d_in[0];
  const float* ln_w  = (const float*)d_in[1];
  const float* ln_b  = (const float*)d_in[2];
  const float* Wu    = (const float*)d_in[3];
  const float* bu    = (const float*)d_in[4];
  const float* Wv    = (const float*)d_in[5];
  const float* bv    = (const float*)d_in[6];
  const float* Wbase = (const float*)d_in[7];
  const float* bbase = (const float*)d_in[8];
  const float* q_w   = (const float*)d_in[9];
  const float* q_b   = (const float*)d_in[10];
  const float* k_w   = (const float*)d_in[11];
  const float* k_b   = (const float*)d_in[12];
  const float* w_rel = (const float*)d_in[13];
  const float* Wo    = (const float*)d_in[14];
  const float* bo    = (const float*)d_in[15];
  float* out = (float*)d_out;

  char* ws = (char*)d_ws;
  ushort* X    = (ushort*)(ws);                     // 4 MB
  ushort* U    = (ushort*)(ws + (4u  << 20));       // 8 MB
  ushort* VT   = (ushort*)(ws + (12u << 20));       // 8 MB
  ushort* BASE = (ushort*)(ws + (20u << 20));       // 2 MB
  ushort* Qb   = (ushort*)(ws + (22u << 20));       // 2 MB
  ushort* Kb   = (ushort*)(ws + (24u << 20));       // 2 MB
  ushort* KVU  = (ushort*)(ws + (26u << 20));       // 8 MB
  ushort* WUT  = (ushort*)(ws + (34u << 20));
  ushort* WVT  = (ushort*)(ws + (34u << 20) + 512*256*2);
  ushort* WBT  = (ushort*)(ws + (34u << 20) + 2*512*256*2);
  ushort* WOT  = (ushort*)(ws + (34u << 20) + 2*512*256*2 + 128*256*2);
  float*  WREP = (float*)(ws + (35u << 20));        // 128 KB

  ln_kernel<<<2048, 256, 0, stream>>>(query, ln_w, ln_b, X);
  prep_kernel<<<1792, 256, 0, stream>>>(Wu, Wv, Wbase, Wo, w_rel,
                                        WUT, WVT, WBT, WOT, WREP);
  gemm_kernel<0><<<dim3(64, 8), 256, 0, stream>>>(X, WUT, bu, U, 8192, 512, 256);
  gemm_kernel<2><<<dim3(64, 8), 256, 0, stream>>>(X, WVT, bv, VT, 8192, 512, 256);
  gemm_kernel<0><<<dim3(64, 2), 256, 0, stream>>>(X, WBT, bbase, BASE, 8192, 128, 256);
  rope_kernel<<<2048, 256, 0, stream>>>(BASE, q_w, q_b, k_w, k_b, Qb, Kb);
  attn_kernel<<<dim3(32, 4, 2), 512, 0, stream>>>(Qb, Kb, VT, U, WREP, KVU);
  gemm_kernel<1><<<dim3(64, 4), 256, 0, stream>>>(KVU, WOT, bo, out, 8192, 256, 512);
}

// Round 14
// 166.232 us; speedup vs baseline: 1.0668x; 1.0668x over previous
//
#include <hip/hip_runtime.h>
#include <hip/hip_bf16.h>
#include <math.h>

typedef __bf16 bf16_8 __attribute__((ext_vector_type(8)));
typedef float f32x4 __attribute__((ext_vector_type(4)));
typedef float f32x16 __attribute__((ext_vector_type(16)));

#define D_ 256
#define S_ 128
#define E_ 512
#define MPE_ 4096
#define B_ 2
#define N_ 4096
#define M_TOT (B_*N_)   // 8192

__device__ __forceinline__ ushort f2b(float f) {
  union { float f; uint u; } x; x.f = f;
  uint r = (x.u + 0x7FFFu + ((x.u >> 16) & 1u)) >> 16;
  return (ushort)r;
}
__device__ __forceinline__ float b2f(ushort b) {
  union { uint u; float f; } x; x.u = ((uint)b) << 16;
  return x.f;
}

__device__ __forceinline__ void gl_lds16(const void* g, void* l) {
  __builtin_amdgcn_global_load_lds(
      (const __attribute__((address_space(1))) void*)g,
      (__attribute__((address_space(3))) void*)l, 16, 0, 0);
}

// ---------------- LayerNorm: one wave per row ----------------
__global__ __launch_bounds__(256) void ln_kernel(const float* __restrict__ q,
    const float* __restrict__ w, const float* __restrict__ b,
    ushort* __restrict__ x) {
  int wid = threadIdx.x >> 6, lane = threadIdx.x & 63;
  int row = blockIdx.x * 4 + wid;
  const float* qr = q + (size_t)row * D_;
  float4 v = *(const float4*)(qr + lane * 4);
  float s  = v.x + v.y + v.z + v.w;
  float ss = v.x*v.x + v.y*v.y + v.z*v.z + v.w*v.w;
  #pragma unroll
  for (int off = 32; off; off >>= 1) {
    s  += __shfl_xor(s, off);
    ss += __shfl_xor(ss, off);
  }
  float mu   = s * (1.0f / 256.0f);
  float var  = ss * (1.0f / 256.0f) - mu * mu;
  float rstd = rsqrtf(var + 1e-5f);
  ushort4 o;
  float vv[4] = {v.x, v.y, v.z, v.w};
  ushort ot[4];
  #pragma unroll
  for (int j = 0; j < 4; ++j) {
    int c = lane * 4 + j;
    ot[j] = f2b((vv[j] - mu) * rstd * w[c] + b[c]);
  }
  o.x = ot[0]; o.y = ot[1]; o.z = ot[2]; o.w = ot[3];
  *(ushort4*)(x + (size_t)row * D_ + lane * 4) = o;
}

// ---------------- prep: all 4 weight transposes + wrep in ONE launch ----------------
__global__ __launch_bounds__(256) void prep_kernel(
    const float* __restrict__ Wu, const float* __restrict__ Wv,
    const float* __restrict__ Wb, const float* __restrict__ Wo,
    const float* __restrict__ w_rel,
    ushort* __restrict__ WUT, ushort* __restrict__ WVT,
    ushort* __restrict__ WBT, ushort* __restrict__ WOT,
    float* __restrict__ wrep) {
  int blk = blockIdx.x, tid = threadIdx.x;
  if (blk < 512) {
    int o = blk * 256 + tid; int c = o >> 8, r = o & 255;
    WUT[o] = f2b(Wu[r * 512 + c]);
  } else if (blk < 1024) {
    int o = (blk - 512) * 256 + tid; int c = o >> 8, r = o & 255;
    WVT[o] = f2b(Wv[r * 512 + c]);
  } else if (blk < 1152) {
    int o = (blk - 1024) * 256 + tid; int c = o >> 8, r = o & 255;
    WBT[o] = f2b(Wb[r * 128 + c]);
  } else if (blk < 1664) {
    int o = (blk - 1152) * 256 + tid; int c = o >> 9, r = o & 511;
    WOT[o] = f2b(Wo[r * 256 + c]);
  } else {
    int idx = (blk - 1664) * 256 + tid;
    int c = idx >> 13, i = idx & 8191;
    int s = i + c; if (s > 8190) s = 8190;
    wrep[idx] = w_rel[s];
  }
}

// ---------------- GEMM: A[M][K] bf16, Bt[N][K] bf16, tile 128x64, BK=64 ----------------
// EPI 0: silu -> bf16 row-major. EPI 1: +bias f32 row-major.
// EPI 2: silu -> bf16 in PV 32x32 B-FRAGMENT order (VF32).
template<int EPI>
__global__ __launch_bounds__(256) void gemm_kernel(
    const ushort* __restrict__ A, const ushort* __restrict__ Bt,
    const float* __restrict__ bias, void* __restrict__ out,
    int M, int N, int K) {
  __shared__ alignas(16) ushort As[128 * 64];
  __shared__ alignas(16) ushort Bs[64 * 64];
  int tid = threadIdx.x;
  int lane = tid & 63, wid = tid >> 6;
  int m0 = blockIdx.x * 128, n0 = blockIdx.y * 64;
  int r16 = lane & 15, kq = lane >> 4;
  f32x4 acc[2][4] = {};
  for (int k0 = 0; k0 < K; k0 += 64) {
    __syncthreads();
    #pragma unroll
    for (int t = 0; t < 4; ++t) {
      int cid = tid + t * 256;
      int row = cid >> 3, c = cid & 7;
      uint4 d = *(const uint4*)(A + ((size_t)(m0 + row) * K + k0 + c * 8));
      *(uint4*)&As[row * 64 + ((c ^ (row & 7)) * 8)] = d;
    }
    #pragma unroll
    for (int t = 0; t < 2; ++t) {
      int cid = tid + t * 256;
      int row = cid >> 3, c = cid & 7;
      uint4 d = *(const uint4*)(Bt + ((size_t)(n0 + row) * K + k0 + c * 8));
      *(uint4*)&Bs[row * 64 + ((c ^ (row & 7)) * 8)] = d;
    }
    __syncthreads();
    #pragma unroll
    for (int ks = 0; ks < 2; ++ks) {
      bf16_8 af[2], bfr[4];
      int c = ks * 4 + kq;
      #pragma unroll
      for (int fm = 0; fm < 2; ++fm) {
        int r = wid * 32 + fm * 16 + r16;
        af[fm] = *(const bf16_8*)&As[r * 64 + ((c ^ (r & 7)) * 8)];
      }
      #pragma unroll
      for (int fn = 0; fn < 4; ++fn) {
        int r = fn * 16 + r16;
        bfr[fn] = *(const bf16_8*)&Bs[r * 64 + ((c ^ (r & 7)) * 8)];
      }
      #pragma unroll
      for (int fm = 0; fm < 2; ++fm)
        #pragma unroll
        for (int fn = 0; fn < 4; ++fn)
          acc[fm][fn] = __builtin_amdgcn_mfma_f32_16x16x32_bf16(af[fm], bfr[fn], acc[fm][fn], 0, 0, 0);
    }
  }
  #pragma unroll
  for (int fm = 0; fm < 2; ++fm)
    #pragma unroll
    for (int fn = 0; fn < 4; ++fn)
      #pragma unroll
      for (int reg = 0; reg < 4; ++reg) {
        int ml = wid * 32 + fm * 16 + kq * 4 + reg;
        int nl = fn * 16 + r16;
        size_t gm = m0 + ml, gn = n0 + nl;
        float val = acc[fm][fn][reg] + bias[gn];
        if (EPI == 0) {
          float y = val / (1.0f + expf(-val));
          ((ushort*)out)[gm * N + gn] = f2b(y);
        } else if (EPI == 2) {
          float y = val / (1.0f + expf(-val));
          int bb = (int)(gm >> 12), n = (int)(gm & 4095);
          int t = n >> 6, nn = n & 63;
          int nh = nn >> 5, nl2 = nn & 31;
          int kb2 = nl2 >> 4, hi = (nl2 >> 3) & 1, j = nl2 & 7;
          int eb = (int)(gn >> 5), l31e = (int)(gn & 31);
          size_t addr = ((((size_t)(bb * 64 + t) * 2 + nh) * 2 + kb2) * 16 + eb) * 512
                      + (hi * 32 + l31e) * 8 + j;
          ((ushort*)out)[addr] = f2b(y);
        } else {
          ((float*)out)[gm * N + gn] = val;
        }
      }
}

// ---------------- RoPE: Q row-major; K in QK 32x32 A-FRAGMENT order (KF32) ----------------
// KF32[((b*64+t)*2+nh)*8 + kb][ (hi*32 + l31)*8 + j ] = K[n][kb*16+hi*8+j], pre-scaled 1/64
__global__ __launch_bounds__(256) void rope_kernel(const ushort* __restrict__ base,
    const float* __restrict__ qw, const float* __restrict__ qb,
    const float* __restrict__ kw, const float* __restrict__ kb_,
    ushort* __restrict__ Q, ushort* __restrict__ KF) {
  int g = blockIdx.x * 256 + threadIdx.x;
  int row = g >> 6, i = g & 63;
  int n = row & (N_ - 1);
  float invf = powf(10000.0f, -(float)i * (1.0f / 64.0f));
  float sv, cv;
  sincosf((float)n * invf, &sv, &cv);
  const float sc = 0.015625f;   // 1/64; (1/64)^2 = 1/MPE
  float b1 = b2f(base[row * S_ + i]), b2 = b2f(base[row * S_ + 64 + i]);
  float x1q = b1 * qw[i] + qb[i], x2q = b2 * qw[64 + i] + qb[64 + i];
  Q[row * S_ + i]      = f2b((x1q * cv - x2q * sv) * sc);
  Q[row * S_ + 64 + i] = f2b((x2q * cv + x1q * sv) * sc);
  float x1k = b1 * kw[i] + kb_[i], x2k = b2 * kw[64 + i] + kb_[64 + i];
  float k1 = (x1k * cv - x2k * sv) * sc;
  float k2 = (x2k * cv + x1k * sv) * sc;
  int bb = row >> 12, t = n >> 6, nn = n & 63;
  int nh = nn >> 5, l31 = nn & 31;
  int kb1 = i >> 4, hi1 = (i >> 3) & 1, j1 = i & 7;
  size_t fb = (size_t)((bb * 64 + t) * 2 + nh) * 8;
  KF[(fb + kb1) * 512 + (hi1 * 32 + l31) * 8 + j1] = f2b(k1);       // k = i
  KF[(fb + 4 + kb1) * 512 + (hi1 * 32 + l31) * 8 + j1] = f2b(k2);   // k = i + 64
}

// ---------------- fused attention: frag-order LDS, in-reg P, counted vmcnt ----------------
// grid (32 m-tiles of 128, 4 e-chunks of 128, 2 b) = 256 blocks, 512 thr (8 waves:
// 4 wg x 2 nh), 128KB LDS (K 4x16KB + V 4x16KB, 4-deep). All LDS reads are
// base + lane*16 (conflict-free, no addr VALU). P stays in registers (swapped
// 32x32 QK + cvt_pk + permlane32_swap). Bias folded into MFMA C-init.
// One barrier/iter ending s_waitcnt vmcnt(4): tile t+1 landed, t+2 in flight.
__global__ __launch_bounds__(512, 2) void attn_kernel(
    const ushort* __restrict__ Q, const ushort* __restrict__ KF,
    const ushort* __restrict__ VF, const ushort* __restrict__ U,
    const float* __restrict__ wrep, ushort* __restrict__ KVU) {
  __shared__ alignas(16) ushort SMEM_[65536];   // 128 KB
  const int tid = threadIdx.x, lane = tid & 63, wid = tid >> 6;
  const int wg = wid >> 1, nh = wid & 1;
  const int b = blockIdx.z, m0 = blockIdx.x * 128, e0 = blockIdx.y * 128;
  const int l31 = lane & 31, hi = lane >> 5;
  const int mrow = m0 + wg * 32 + l31;

  // bias: idx = bbase + 64t + 8rg + q = 4095 + n - m, always in [0,8190]
  const int bbase = 4095 + nh * 32 + 4 * hi - mrow;
  const int csel = bbase & 3;
  const float* wrow = wrep + csel * 8192 + (bbase - csel);

  // Q fragments (B-operand: col = m = l31, k = kb*16 + hi*8 + j)
  bf16_8 qf[8];
  #pragma unroll
  for (int kb = 0; kb < 8; ++kb)
    qf[kb] = *(const bf16_8*)(Q + ((size_t)(b * N_ + mrow) * S_ + kb * 16 + hi * 8));

  auto stage_kv = [&](int bi, int t) {
    const ushort* ksrc = KF + (size_t)(b * 64 + t) * 8192;
    #pragma unroll
    for (int tt = 0; tt < 2; ++tt) {
      int cb = tt * 8 + wid;                      // chunk 0..15 (1KB each)
      gl_lds16(ksrc + cb * 512 + lane * 8, SMEM_ + bi * 8192 + cb * 512);
    }
    #pragma unroll
    for (int tt = 0; tt < 2; ++tt) {
      int f = tt * 8 + wid;
      int nh2 = f >> 3, kb2 = (f >> 2) & 1, ebl = f & 3;
      size_t fragidx = (((size_t)(b * 64 + t) * 2 + nh2) * 2 + kb2) * 16 + (e0 >> 5) + ebl;
      gl_lds16(VF + fragidx * 512 + lane * 8, SMEM_ + 32768 + bi * 8192 + f * 512);
    }
  };

  f32x16 acc[4] = {};
  uint4 paA[2], paB[2];

  auto do_pv = [&](int vb, const uint4 (&paR)[2]) {
    const ushort* vsb = SMEM_ + 32768 + vb * 8192;
    __builtin_amdgcn_s_setprio(1);
    #pragma unroll
    for (int kb = 0; kb < 2; ++kb) {
      bf16_8 pa = *(const bf16_8*)&paR[kb];
      #pragma unroll
      for (int et = 0; et < 4; ++et) {
        bf16_8 vf = *(const bf16_8*)(vsb + (nh * 8 + kb * 4 + et) * 512 + lane * 8);
        acc[et] = __builtin_amdgcn_mfma_f32_32x32x16_bf16(pa, vf, acc[et], 0, 0, 0);
      }
    }
    __builtin_amdgcn_s_setprio(0);
  };

  auto body = [&](int t, int CUR, int PRV, int NXT, uint4 (&paW)[2],
                  const uint4 (&paR)[2], bool doPV, bool doStage) {
    // ---- bias loads FIRST (auto-wait keeps t+2 stages in flight) ----
    float4 b4[4];
    #pragma unroll
    for (int rg = 0; rg < 4; ++rg)
      b4[rg] = *(const float4*)(wrow + 64 * t + 8 * rg);
    __builtin_amdgcn_sched_barrier(0);
    if (doStage) stage_kv(NXT, t + 2);
    __builtin_amdgcn_sched_barrier(0);
    // ---- QK: s0 = K_frag x Q_frag + bias (C-init) ----
    const ushort* ksb = SMEM_ + CUR * 8192;
    f32x16 s0;
    #pragma unroll
    for (int rg = 0; rg < 4; ++rg) {
      s0[4*rg+0] = b4[rg].x; s0[4*rg+1] = b4[rg].y;
      s0[4*rg+2] = b4[rg].z; s0[4*rg+3] = b4[rg].w;
    }
    __builtin_amdgcn_s_setprio(1);
    #pragma unroll
    for (int kb = 0; kb < 8; ++kb) {
      bf16_8 kf = *(const bf16_8*)(ksb + (nh * 8 + kb) * 512 + lane * 8);
      s0 = __builtin_amdgcn_mfma_f32_32x32x16_bf16(kf, qf[kb], s0, 0, 0, 0);
    }
    __builtin_amdgcn_s_setprio(0);
    // ---- PV(t-1): in-reg P + V frags from buffer PRV ----
    if (doPV) do_pv(PRV, paR);
    // ---- transform: relu^2 -> bf16 -> permlane -> paW ----
    uint w0[4], w1[4];
    #pragma unroll
    for (int rg = 0; rg < 4; ++rg) {
      float t0 = fmaxf(s0[4*rg+0], 0.f); t0 *= t0;
      float t1 = fmaxf(s0[4*rg+1], 0.f); t1 *= t1;
      float t2 = fmaxf(s0[4*rg+2], 0.f); t2 *= t2;
      float t3 = fmaxf(s0[4*rg+3], 0.f); t3 *= t3;
      asm("v_cvt_pk_bf16_f32 %0, %1, %2" : "=v"(w0[rg]) : "v"(t0), "v"(t1));
      asm("v_cvt_pk_bf16_f32 %0, %1, %2" : "=v"(w1[rg]) : "v"(t2), "v"(t3));
    }
    #pragma unroll
    for (int kb = 0; kb < 2; ++kb) {
      int rs = 2 * kb;
      uint x0 = w0[rs], y0 = w0[rs + 1];
      asm("v_permlane32_swap_b32 %0, %1" : "+v"(x0), "+v"(y0));
      uint x1 = w1[rs], y1 = w1[rs + 1];
      asm("v_permlane32_swap_b32 %0, %1" : "+v"(x1), "+v"(y1));
      uint4 pk; pk.x = x0; pk.y = x1; pk.z = y0; pk.w = y1;
      paW[kb] = pk;
    }
    asm volatile("s_waitcnt vmcnt(4)" ::: "memory");   // t+1 landed; t+2 in flight
    __builtin_amdgcn_s_barrier();
  };

  // prologue: stage tiles 0 and 1
  stage_kv(0, 0);
  stage_kv(1, 1);
  asm volatile("s_waitcnt vmcnt(4)" ::: "memory");     // tile 0 landed
  __builtin_amdgcn_s_barrier();

  // 4-body unrolled loop: t = 4u+k; buffers = k; pa parity = k&1
  for (int u = 0; u < 16; ++u) {
    int t0i = 4 * u;
    body(t0i,     0, 3, 2, paA, paB, t0i > 0, t0i     <= 61);
    body(t0i + 1, 1, 0, 3, paB, paA, true,    t0i + 1 <= 61);
    body(t0i + 2, 2, 1, 0, paA, paB, true,    t0i + 2 <= 61);
    body(t0i + 3, 3, 2, 1, paB, paA, true,    t0i + 3 <= 61);
  }
  // drain: PV(63) — V(63) in buffer 3, paB holds P(63)
  asm volatile("s_waitcnt vmcnt(0)" ::: "memory");
  do_pv(3, paB);

  // ---- cross-nh reduction through LDS (once) ----
  __syncthreads();
  float* red = (float*)SMEM_;
  if (nh == 1) {
    #pragma unroll
    for (int et = 0; et < 4; ++et)
      #pragma unroll
      for (int rg4 = 0; rg4 < 4; ++rg4) {
        float4 w;
        w.x = acc[et][4*rg4+0]; w.y = acc[et][4*rg4+1];
        w.z = acc[et][4*rg4+2]; w.w = acc[et][4*rg4+3];
        *(float4*)&red[wg * 4096 + et * 1024 + rg4 * 256 + lane * 4] = w;
      }
  }
  __syncthreads();
  if (nh == 0) {
    #pragma unroll
    for (int et = 0; et < 4; ++et)
      #pragma unroll
      for (int rg4 = 0; rg4 < 4; ++rg4) {
        float4 r = *(const float4*)&red[wg * 4096 + et * 1024 + rg4 * 256 + lane * 4];
        acc[et][4*rg4+0] += r.x; acc[et][4*rg4+1] += r.y;
        acc[et][4*rg4+2] += r.z; acc[et][4*rg4+3] += r.w;
      }
    // ---- epilogue: KVU = bf16(u * acc); D: col=e(l31), row m=(reg&3)+8(reg>>2)+4hi ----
    #pragma unroll
    for (int et = 0; et < 4; ++et)
      #pragma unroll
      for (int reg = 0; reg < 16; ++reg) {
        int ml = (reg & 3) + 8 * (reg >> 2) + 4 * hi;
        size_t grow = (size_t)b * N_ + m0 + wg * 32 + ml;
        size_t ge = e0 + et * 32 + l31;
        float uu = b2f(U[grow * E_ + ge]);
        KVU[grow * E_ + ge] = f2b(uu * acc[et][reg]);
      }
  }
}

extern "C" void kernel_launch(void* const* d_in, const int* in_sizes, int n_in,
                              void* d_out, int out_size, void* d_ws, size_t ws_size,
                              hipStream_t stream) {
  const float* query = (const float*)d_in[0];
  const float* ln_w  = (const float*)d_in[1];
  const float* ln_b  = (const float*)d_in[2];
  const float* Wu    = (const float*)d_in[3];
  const float* bu    = (const float*)d_in[4];
  const float* Wv    = (const float*)d_in[5];
  const float* bv    = (const float*)d_in[6];
  const float* Wbase = (const float*)d_in[7];
  const float* bbase = (const float*)d_in[8];
  const float* q_w   = (const float*)d_in[9];
  const float* q_b   = (const float*)d_in[10];
  const float* k_w   = (const float*)d_in[11];
  const float* k_b   = (const float*)d_in[12];
  const float* w_rel = (const float*)d_in[13];
  const float* Wo    = (const float*)d_in[14];
  const float* bo    = (const float*)d_in[15];
  float* out = (float*)d_out;

  char* ws = (char*)d_ws;
  ushort* X    = (ushort*)(ws);                     // 4 MB
  ushort* U    = (ushort*)(ws + (4u  << 20));       // 8 MB
  ushort* VF   = (ushort*)(ws + (12u << 20));       // 8 MB (32x32 B-fragment order)
  ushort* BASE = (ushort*)(ws + (20u << 20));       // 2 MB
  ushort* Qb   = (ushort*)(ws + (22u << 20));       // 2 MB
  ushort* KF   = (ushort*)(ws + (24u << 20));       // 2 MB (32x32 A-fragment order)
  ushort* KVU  = (ushort*)(ws + (26u << 20));       // 8 MB
  ushort* WUT  = (ushort*)(ws + (34u << 20));
  ushort* WVT  = (ushort*)(ws + (34u << 20) + 512*256*2);
  ushort* WBT  = (ushort*)(ws + (34u << 20) + 2*512*256*2);
  ushort* WOT  = (ushort*)(ws + (34u << 20) + 2*512*256*2 + 128*256*2);
  float*  WREP = (float*)(ws + (35u << 20));        // 128 KB

  ln_kernel<<<2048, 256, 0, stream>>>(query, ln_w, ln_b, X);
  prep_kernel<<<1792, 256, 0, stream>>>(Wu, Wv, Wbase, Wo, w_rel,
                                        WUT, WVT, WBT, WOT, WREP);
  gemm_kernel<0><<<dim3(64, 8), 256, 0, stream>>>(X, WUT, bu, U, 8192, 512, 256);
  gemm_kernel<2><<<dim3(64, 8), 256, 0, stream>>>(X, WVT, bv, VF, 8192, 512, 256);
  gemm_kernel<0><<<dim3(64, 2), 256, 0, stream>>>(X, WBT, bbase, BASE, 8192, 128, 256);
  rope_kernel<<<2048, 256, 0, stream>>>(BASE, q_w, q_b, k_w, k_b, Qb, KF);
  attn_kernel<<<dim3(32, 4, 2), 512, 0, stream>>>(Qb, KF, VF, U, WREP, KVU);
  gemm_kernel<1><<<dim3(64, 4), 256, 0, stream>>>(KVU, WOT, bo, out, 8192, 256, 512);
}